// Round 4
// baseline (263.386 us; speedup 1.0000x reference)
//
#include <hip/hip_runtime.h>
#include <hip/hip_fp16.h>
#include <stdint.h>
#include <math.h>

#define KB 512
#define KT 2048
#define KS 16
#define KPD 4
#define TILE 128
#define NTILE (KT / TILE)

// ---------------- shared helpers ----------------
__device__ __forceinline__ float softplus_f(float x) {
    float ax = fabsf(x);
    float e  = __expf(-ax);
    return fmaxf(x, 0.0f) + __logf(1.0f + e);
}
__device__ __forceinline__ float sigmoid_f(float x) {
    return __builtin_amdgcn_rcpf(1.0f + __expf(-x));
}

__device__ __forceinline__ void mlp16(const float4 pv,
    const float* __restrict__ W1, const float* __restrict__ b1,
    const float* __restrict__ W2, const float* __restrict__ b2,
    float* __restrict__ acc)
{
#pragma unroll
    for (int j = 0; j < KS; ++j) acc[j] = b2[j];
#pragma unroll 4
    for (int k = 0; k < 64; ++k) {
        float hk = b1[k];
        hk = fmaf(pv.x, W1[k],       hk);
        hk = fmaf(pv.y, W1[64 + k],  hk);
        hk = fmaf(pv.z, W1[128 + k], hk);
        hk = fmaf(pv.w, W1[192 + k], hk);
        hk = fmaxf(hk, 0.0f);
#pragma unroll
        for (int j = 0; j < KS; ++j) acc[j] = fmaf(hk, W2[k * KS + j], acc[j]);
    }
}

// ---------------- K1: embarrassingly-parallel MLPs ----------------
// ws layout: qr_ws[b][t][s] (u32 = fp16 Q | fp16 R << 16), g_ws[b][t] (f32)
__global__ __launch_bounds__(256) void mlp_kernel(
    const float* __restrict__ p,
    const float* __restrict__ Wq1, const float* __restrict__ bq1,
    const float* __restrict__ Wq2, const float* __restrict__ bq2,
    const float* __restrict__ Wr1, const float* __restrict__ br1,
    const float* __restrict__ Wr2, const float* __restrict__ br2,
    const float* __restrict__ Wg1, const float* __restrict__ bg1,
    const float* __restrict__ Wg2, const float* __restrict__ bg2,
    uint32_t* __restrict__ qr_ws, float* __restrict__ g_ws)
{
    const int idx = blockIdx.x * 256 + threadIdx.x;   // global (b,t)
    const float4 pv = reinterpret_cast<const float4*>(p)[idx];

    float accQ[KS], accR[KS];
    mlp16(pv, Wq1, bq1, Wq2, bq2, accQ);
    mlp16(pv, Wr1, br1, Wr2, br2, accR);

    float ag = bg2[0];
#pragma unroll 4
    for (int k = 0; k < 32; ++k) {
        float hk = bg1[k];
        hk = fmaf(pv.x, Wg1[k],      hk);
        hk = fmaf(pv.y, Wg1[32 + k], hk);
        hk = fmaf(pv.z, Wg1[64 + k], hk);
        hk = fmaf(pv.w, Wg1[96 + k], hk);
        hk = fmaxf(hk, 0.0f);
        ag = fmaf(hk, Wg2[k], ag);
    }
    g_ws[idx] = sigmoid_f(ag);

    uint32_t wv[KS];
#pragma unroll
    for (int j = 0; j < KS; ++j) {
        float Qv = softplus_f(accQ[j]) + 1e-8f;
        float Rv = softplus_f(accR[j]) + 1e-8f;
        uint32_t lo = (uint32_t)__half_as_ushort(__float2half_rn(Qv));
        uint32_t hi = (uint32_t)__half_as_ushort(__float2half_rn(Rv));
        wv[j] = lo | (hi << 16);
    }
    // [b][t][s]: 16 contiguous u32 per (b,t) -> 4 uint4 stores
    uint4* qb = reinterpret_cast<uint4*>(qr_ws + ((size_t)idx << 4));
#pragma unroll
    for (int i = 0; i < 4; ++i)
        qb[i] = make_uint4(wv[4*i], wv[4*i+1], wv[4*i+2], wv[4*i+3]);
}

// ---------------- K2: LDS-staged sequential scan ----------------
// One wave per b. All 64 lanes issue global_load_lds for tile k+1 (async DMA),
// lanes 0-15 run the 16 serial chains on tile k from LDS. One vmcnt(0) per tile.
__global__ __launch_bounds__(64, 4) void scan_kernel(
    const uint32_t* __restrict__ qr_ws, const float* __restrict__ g_ws,
    const float* __restrict__ z, const float* __restrict__ mu0,
    const float* __restrict__ P0, float* __restrict__ out)
{
    __shared__ uint32_t sQR[2][TILE][KS];   // 16 KB
    __shared__ float    sZ [2][TILE][KS];   // 16 KB
    __shared__ float    sG [2][TILE];       //  1 KB

    const int b = blockIdx.x;
    const int lane = threadIdx.x;           // 0..63
    const uint32_t* qb = qr_ws + (size_t)b * KT * KS;
    const float* zb = z + (size_t)b * KT * KS;
    const float* gb = g_ws + (size_t)b * KT;
    float* ob = out + (size_t)b * KT * KS;

    auto stage = [&](int tile, int buf) {
        const char* zsrc = (const char*)(zb + (size_t)tile * TILE * KS) + lane * 16;
        const char* qsrc = (const char*)(qb + (size_t)tile * TILE * KS) + lane * 16;
#pragma unroll
        for (int i = 0; i < 8; ++i) {
            __builtin_amdgcn_global_load_lds(
                (const __attribute__((address_space(1))) uint32_t*)(zsrc + i * 1024),
                (__attribute__((address_space(3))) uint32_t*)&sZ[buf][i * 16][0],
                16, 0, 0);
            __builtin_amdgcn_global_load_lds(
                (const __attribute__((address_space(1))) uint32_t*)(qsrc + i * 1024),
                (__attribute__((address_space(3))) uint32_t*)&sQR[buf][i * 16][0],
                16, 0, 0);
        }
        const char* gsrc = (const char*)(gb + (size_t)tile * TILE) + lane * 4;
#pragma unroll
        for (int i = 0; i < 2; ++i) {
            __builtin_amdgcn_global_load_lds(
                (const __attribute__((address_space(1))) uint32_t*)(gsrc + i * 256),
                (__attribute__((address_space(3))) uint32_t*)&sG[buf][i * 64],
                4, 0, 0);
        }
    };

    float mu = 0.0f, Pv = 0.0f;
    if (lane < KS) {
        mu = mu0[b * KS + lane];
        Pv = P0[b * KS + lane];
    }

    stage(0, 0);
    asm volatile("s_waitcnt vmcnt(0)" ::: "memory");
    __builtin_amdgcn_sched_barrier(0);

    for (int k = 0; k < NTILE; ++k) {
        const int buf = k & 1;
        if (k + 1 < NTILE) stage(k + 1, buf ^ 1);
        if (lane < KS) {
            const int s = lane;
            float* op = ob + (size_t)k * TILE * KS + s;
#pragma unroll 4
            for (int t = 0; t < TILE; ++t) {
                uint32_t w = sQR[buf][t][s];
                float zv = sZ[buf][t][s];
                float gv = sG[buf][t];
                float Q = __half2float(__ushort_as_half((unsigned short)(w & 0xffffu)));
                float R = __half2float(__ushort_as_half((unsigned short)(w >> 16)));
                float Pp = Pv + Q;
                float K0 = Pp * __builtin_amdgcn_rcpf(Pp + R);
                float Kk = __builtin_amdgcn_fmed3f(K0, 1e-6f, 0.95f);
                mu = fmaf(gv * Kk, zv - mu, mu);
                Pv = fmaf(-Kk, Pp, Pp);
                op[(size_t)t * KS] = mu;
            }
        }
        // drain: tile k+1 loads complete (and tile k stores) before next iter reads LDS
        asm volatile("s_waitcnt vmcnt(0)" ::: "memory");
        __builtin_amdgcn_sched_barrier(0);
    }
}

// ---------------- fallback: R2 fused kernel (if ws too small) ----------------
#define KTT 128
#define KNT (KT / KTT)
#define SROW (KS + 1)

__global__ __launch_bounds__(320, 2) void kalman_fused(
    const float* __restrict__ z, const float* __restrict__ p,
    const float* __restrict__ mu0, const float* __restrict__ P0,
    const float* __restrict__ Wq1, const float* __restrict__ bq1,
    const float* __restrict__ Wq2, const float* __restrict__ bq2,
    const float* __restrict__ Wr1, const float* __restrict__ br1,
    const float* __restrict__ Wr2, const float* __restrict__ br2,
    const float* __restrict__ Wg1, const float* __restrict__ bg1,
    const float* __restrict__ Wg2, const float* __restrict__ bg2,
    float* __restrict__ out)
{
    __shared__ float sQ[2][KTT][SROW];
    __shared__ float sR[2][KTT][SROW];
    __shared__ float sZf[2][KTT][KS];
    __shared__ float sGf[2][KTT];

    const int b = blockIdx.x;
    const int tid = threadIdx.x;
    const float* __restrict__ zb = z + (size_t)b * KT * KS;
    const float* __restrict__ pb = p + (size_t)b * KT * KPD;
    float* __restrict__ outb = out + (size_t)b * KT * KS;

    const bool is_mlp = (tid < 256);

    auto do_mlp_tile = [&](int tile, int buf) {
        const int tt = tid & (KTT - 1);
        const int t = tile * KTT + tt;
        const float4 pv = *reinterpret_cast<const float4*>(pb + (size_t)t * KPD);
        float acc[KS];
        if (tid < KTT) {
            mlp16(pv, Wq1, bq1, Wq2, bq2, acc);
#pragma unroll
            for (int j = 0; j < KS; ++j)
                sQ[buf][tt][j] = softplus_f(acc[j]) + 1e-8f;
            float ag = bg2[0];
#pragma unroll 8
            for (int k = 0; k < 32; ++k) {
                float hk = bg1[k];
                hk = fmaf(pv.x, Wg1[k],      hk);
                hk = fmaf(pv.y, Wg1[32 + k], hk);
                hk = fmaf(pv.z, Wg1[64 + k], hk);
                hk = fmaf(pv.w, Wg1[96 + k], hk);
                hk = fmaxf(hk, 0.0f);
                ag = fmaf(hk, Wg2[k], ag);
            }
            sGf[buf][tt] = sigmoid_f(ag);
        } else {
            mlp16(pv, Wr1, br1, Wr2, br2, acc);
#pragma unroll
            for (int j = 0; j < KS; ++j)
                sR[buf][tt][j] = softplus_f(acc[j]) + 1e-8f;
        }
        const float4* __restrict__ zt =
            reinterpret_cast<const float4*>(zb + (size_t)tile * KTT * KS);
        float4* __restrict__ zd = reinterpret_cast<float4*>(&sZf[buf][0][0]);
        zd[tid] = zt[tid];
        zd[tid + 256] = zt[tid + 256];
    };

    float mu = 0.0f, Pv = 0.0f;
    if (!is_mlp) {
        const int lane = tid - 256;
        if (lane < KS) {
            mu = mu0[(size_t)b * KS + lane];
            Pv = P0[(size_t)b * KS + lane];
        }
    }

    if (is_mlp) do_mlp_tile(0, 0);
    __syncthreads();

    for (int k = 0; k < KNT; ++k) {
        const int cur = k & 1;
        if (is_mlp) {
            if (k + 1 < KNT) do_mlp_tile(k + 1, cur ^ 1);
        } else {
            const int lane = tid - 256;
            if (lane < KS) {
                const int s = lane;
                for (int tt = 0; tt < KTT; ++tt) {
                    const float Ppred = Pv + sQ[cur][tt][s];
                    float Kk = Ppred * __builtin_amdgcn_rcpf(Ppred + sR[cur][tt][s]);
                    Kk = __builtin_amdgcn_fmed3f(Kk, 1e-6f, 0.95f);
                    mu = fmaf(sGf[cur][tt] * Kk, sZf[cur][tt][s] - mu, mu);
                    Pv = fmaf(-Kk, Ppred, Ppred);
                    outb[(size_t)(k * KTT + tt) * KS + s] = mu;
                }
            }
        }
        __syncthreads();
    }
}

// ---------------- launcher ----------------
extern "C" void kernel_launch(void* const* d_in, const int* in_sizes, int n_in,
                              void* d_out, int out_size, void* d_ws, size_t ws_size,
                              hipStream_t stream) {
    const float* z   = (const float*)d_in[0];
    const float* p   = (const float*)d_in[1];
    const float* mu0 = (const float*)d_in[2];
    const float* P0  = (const float*)d_in[3];
    const float* Wq1 = (const float*)d_in[4];
    const float* bq1 = (const float*)d_in[5];
    const float* Wq2 = (const float*)d_in[6];
    const float* bq2 = (const float*)d_in[7];
    const float* Wr1 = (const float*)d_in[8];
    const float* br1 = (const float*)d_in[9];
    const float* Wr2 = (const float*)d_in[10];
    const float* br2 = (const float*)d_in[11];
    const float* Wg1 = (const float*)d_in[12];
    const float* bg1 = (const float*)d_in[13];
    const float* Wg2 = (const float*)d_in[14];
    const float* bg2 = (const float*)d_in[15];
    float* out = (float*)d_out;

    const size_t QR_BYTES = (size_t)KB * KS * KT * 4;   // 67,108,864
    const size_t G_BYTES  = (size_t)KB * KT * 4;        //  4,194,304

    if (ws_size >= QR_BYTES + G_BYTES) {
        uint32_t* qr_ws = (uint32_t*)d_ws;
        float* g_ws = (float*)((char*)d_ws + QR_BYTES);
        hipLaunchKernelGGL(mlp_kernel, dim3((KB * KT) / 256), dim3(256), 0, stream,
                           p, Wq1, bq1, Wq2, bq2, Wr1, br1, Wr2, br2,
                           Wg1, bg1, Wg2, bg2, qr_ws, g_ws);
        hipLaunchKernelGGL(scan_kernel, dim3(KB), dim3(64), 0, stream,
                           qr_ws, g_ws, z, mu0, P0, out);
    } else {
        hipLaunchKernelGGL(kalman_fused, dim3(KB), dim3(320), 0, stream,
                           z, p, mu0, P0, Wq1, bq1, Wq2, bq2,
                           Wr1, br1, Wr2, br2, Wg1, bg1, Wg2, bg2, out);
    }
}

// Round 5
// 192.731 us; speedup vs baseline: 1.3666x; 1.3666x over previous
//
#include <hip/hip_runtime.h>
#include <hip/hip_fp16.h>
#include <stdint.h>
#include <math.h>

#define KB 512
#define KT 2048
#define KS 16
#define KPD 4
#define TILE 128
#define NTILE (KT / TILE)

// ---------------- shared helpers ----------------
__device__ __forceinline__ float softplus_f(float x) {
    float ax = fabsf(x);
    float e  = __expf(-ax);
    return fmaxf(x, 0.0f) + __logf(1.0f + e);
}
__device__ __forceinline__ float sigmoid_f(float x) {
    return __builtin_amdgcn_rcpf(1.0f + __expf(-x));
}

__device__ __forceinline__ void mlp16(const float4 pv,
    const float* __restrict__ W1, const float* __restrict__ b1,
    const float* __restrict__ W2, const float* __restrict__ b2,
    float* __restrict__ acc)
{
#pragma unroll
    for (int j = 0; j < KS; ++j) acc[j] = b2[j];
#pragma unroll 4
    for (int k = 0; k < 64; ++k) {
        float hk = b1[k];
        hk = fmaf(pv.x, W1[k],       hk);
        hk = fmaf(pv.y, W1[64 + k],  hk);
        hk = fmaf(pv.z, W1[128 + k], hk);
        hk = fmaf(pv.w, W1[192 + k], hk);
        hk = fmaxf(hk, 0.0f);
#pragma unroll
        for (int j = 0; j < KS; ++j) acc[j] = fmaf(hk, W2[k * KS + j], acc[j]);
    }
}

// ---------------- K1: embarrassingly-parallel MLPs ----------------
// ws layout: qr_ws[b][t][s] (u32 = fp16 Q | fp16 R << 16), g_ws[b][t] (f32)
__global__ __launch_bounds__(256) void mlp_kernel(
    const float* __restrict__ p,
    const float* __restrict__ Wq1, const float* __restrict__ bq1,
    const float* __restrict__ Wq2, const float* __restrict__ bq2,
    const float* __restrict__ Wr1, const float* __restrict__ br1,
    const float* __restrict__ Wr2, const float* __restrict__ br2,
    const float* __restrict__ Wg1, const float* __restrict__ bg1,
    const float* __restrict__ Wg2, const float* __restrict__ bg2,
    uint32_t* __restrict__ qr_ws, float* __restrict__ g_ws)
{
    const int idx = blockIdx.x * 256 + threadIdx.x;   // global (b,t)
    const float4 pv = reinterpret_cast<const float4*>(p)[idx];

    float accQ[KS], accR[KS];
    mlp16(pv, Wq1, bq1, Wq2, bq2, accQ);
    mlp16(pv, Wr1, br1, Wr2, br2, accR);

    float ag = bg2[0];
#pragma unroll 4
    for (int k = 0; k < 32; ++k) {
        float hk = bg1[k];
        hk = fmaf(pv.x, Wg1[k],      hk);
        hk = fmaf(pv.y, Wg1[32 + k], hk);
        hk = fmaf(pv.z, Wg1[64 + k], hk);
        hk = fmaf(pv.w, Wg1[96 + k], hk);
        hk = fmaxf(hk, 0.0f);
        ag = fmaf(hk, Wg2[k], ag);
    }
    g_ws[idx] = sigmoid_f(ag);

    uint32_t wv[KS];
#pragma unroll
    for (int j = 0; j < KS; ++j) {
        float Qv = softplus_f(accQ[j]) + 1e-8f;
        float Rv = softplus_f(accR[j]) + 1e-8f;
        uint32_t lo = (uint32_t)__half_as_ushort(__float2half_rn(Qv));
        uint32_t hi = (uint32_t)__half_as_ushort(__float2half_rn(Rv));
        wv[j] = lo | (hi << 16);
    }
    uint4* qb = reinterpret_cast<uint4*>(qr_ws + ((size_t)idx << 4));
#pragma unroll
    for (int i = 0; i < 4; ++i)
        qb[i] = make_uint4(wv[4*i], wv[4*i+1], wv[4*i+2], wv[4*i+3]);
}

// ---------------- K2: LDS-staged scan, hand-pipelined registers ----------------
__device__ __forceinline__ float h2f_lo(uint32_t w) {
    return __half2float(__ushort_as_half((unsigned short)(w & 0xffffu)));
}
__device__ __forceinline__ float h2f_hi(uint32_t w) {
    return __half2float(__ushort_as_half((unsigned short)(w >> 16)));
}

struct G8 {
    uint32_t qr[8];
    float    z[8];
    float    g[8];
};

__device__ __forceinline__ void ldg8(G8& gr,
    const uint32_t (*__restrict__ qrT)[KS], const float (*__restrict__ zT)[KS],
    const float* __restrict__ gT, int t0, int s)
{
#pragma unroll
    for (int i = 0; i < 8; ++i) gr.qr[i] = qrT[t0 + i][s];
#pragma unroll
    for (int i = 0; i < 8; ++i) gr.z[i] = zT[t0 + i][s];
    *reinterpret_cast<float4*>(&gr.g[0]) = *reinterpret_cast<const float4*>(&gT[t0]);
    *reinterpret_cast<float4*>(&gr.g[4]) = *reinterpret_cast<const float4*>(&gT[t0 + 4]);
}

__device__ __forceinline__ void chain8(const G8& gr, float& mu, float& Pv,
                                       float* __restrict__ op)
{
#pragma unroll
    for (int i = 0; i < 8; ++i) {
        float Q  = h2f_lo(gr.qr[i]);
        float R  = h2f_hi(gr.qr[i]);
        float Pp = Pv + Q;
        float K0 = Pp * __builtin_amdgcn_rcpf(Pp + R);
        float Kk = __builtin_amdgcn_fmed3f(K0, 1e-6f, 0.95f);
        mu = fmaf(gr.g[i] * Kk, gr.z[i] - mu, mu);
        Pv = fmaf(-Kk, Pp, Pp);
        op[i * KS] = mu;
    }
}

__global__ __launch_bounds__(64) void scan_kernel(
    const uint32_t* __restrict__ qr_ws, const float* __restrict__ g_ws,
    const float* __restrict__ z, const float* __restrict__ mu0,
    const float* __restrict__ P0, float* __restrict__ out)
{
    __shared__ uint32_t sQR[2][TILE][KS];   // 16 KB
    __shared__ float    sZ [2][TILE][KS];   // 16 KB
    __shared__ float    sG [2][TILE];       //  1 KB

    const int b = blockIdx.x;
    const int lane = threadIdx.x;           // 0..63
    const uint32_t* qb = qr_ws + (size_t)b * KT * KS;
    const float* zb = z + (size_t)b * KT * KS;
    const float* gb = g_ws + (size_t)b * KT;
    float* ob = out + (size_t)b * KT * KS;

    auto stage = [&](int tile, int buf) {
        const char* zsrc = (const char*)(zb + (size_t)tile * TILE * KS) + lane * 16;
        const char* qsrc = (const char*)(qb + (size_t)tile * TILE * KS) + lane * 16;
#pragma unroll
        for (int i = 0; i < 8; ++i) {
            __builtin_amdgcn_global_load_lds(
                (const __attribute__((address_space(1))) uint32_t*)(zsrc + i * 1024),
                (__attribute__((address_space(3))) uint32_t*)&sZ[buf][i * 16][0],
                16, 0, 0);
            __builtin_amdgcn_global_load_lds(
                (const __attribute__((address_space(1))) uint32_t*)(qsrc + i * 1024),
                (__attribute__((address_space(3))) uint32_t*)&sQR[buf][i * 16][0],
                16, 0, 0);
        }
        const char* gsrc = (const char*)(gb + (size_t)tile * TILE) + lane * 4;
#pragma unroll
        for (int i = 0; i < 2; ++i) {
            __builtin_amdgcn_global_load_lds(
                (const __attribute__((address_space(1))) uint32_t*)(gsrc + i * 256),
                (__attribute__((address_space(3))) uint32_t*)&sG[buf][i * 64],
                4, 0, 0);
        }
    };

    float mu = 0.0f, Pv = 0.0f;
    if (lane < KS) {
        mu = mu0[b * KS + lane];
        Pv = P0[b * KS + lane];
    }

    stage(0, 0);
    asm volatile("s_waitcnt vmcnt(0)" ::: "memory");
    __builtin_amdgcn_sched_barrier(0);

    for (int k = 0; k < NTILE; ++k) {
        const int buf = k & 1;
        if (k + 1 < NTILE) stage(k + 1, buf ^ 1);
        if (lane < KS) {
            const int s = lane;
            const uint32_t (*__restrict__ qrT)[KS] = sQR[buf];
            const float (*__restrict__ zT)[KS] = sZ[buf];
            const float* __restrict__ gT = sG[buf];
            float* op = ob + (size_t)k * TILE * KS + s;

            G8 A, B;
            ldg8(A, qrT, zT, gT, 0, s);
            for (int j = 0; j < 7; ++j) {
                const int t0 = 16 * j;
                ldg8(B, qrT, zT, gT, t0 + 8, s);
                chain8(A, mu, Pv, op + (size_t)t0 * KS);
                ldg8(A, qrT, zT, gT, t0 + 16, s);
                chain8(B, mu, Pv, op + (size_t)(t0 + 8) * KS);
            }
            ldg8(B, qrT, zT, gT, 120, s);
            chain8(A, mu, Pv, op + (size_t)112 * KS);
            chain8(B, mu, Pv, op + (size_t)120 * KS);
        }
        // staging for tile k+1 (and this tile's stores) must land before buffers swap
        asm volatile("s_waitcnt vmcnt(0)" ::: "memory");
        __builtin_amdgcn_sched_barrier(0);
    }
}

// ---------------- fallback: fused kernel (if ws too small) ----------------
#define KTT 128
#define KNT (KT / KTT)
#define SROW (KS + 1)

__global__ __launch_bounds__(320, 2) void kalman_fused(
    const float* __restrict__ z, const float* __restrict__ p,
    const float* __restrict__ mu0, const float* __restrict__ P0,
    const float* __restrict__ Wq1, const float* __restrict__ bq1,
    const float* __restrict__ Wq2, const float* __restrict__ bq2,
    const float* __restrict__ Wr1, const float* __restrict__ br1,
    const float* __restrict__ Wr2, const float* __restrict__ br2,
    const float* __restrict__ Wg1, const float* __restrict__ bg1,
    const float* __restrict__ Wg2, const float* __restrict__ bg2,
    float* __restrict__ out)
{
    __shared__ float sQ[2][KTT][SROW];
    __shared__ float sR[2][KTT][SROW];
    __shared__ float sZf[2][KTT][KS];
    __shared__ float sGf[2][KTT];

    const int b = blockIdx.x;
    const int tid = threadIdx.x;
    const float* __restrict__ zb = z + (size_t)b * KT * KS;
    const float* __restrict__ pb = p + (size_t)b * KT * KPD;
    float* __restrict__ outb = out + (size_t)b * KT * KS;

    const bool is_mlp = (tid < 256);

    auto do_mlp_tile = [&](int tile, int buf) {
        const int tt = tid & (KTT - 1);
        const int t = tile * KTT + tt;
        const float4 pv = *reinterpret_cast<const float4*>(pb + (size_t)t * KPD);
        float acc[KS];
        if (tid < KTT) {
            mlp16(pv, Wq1, bq1, Wq2, bq2, acc);
#pragma unroll
            for (int j = 0; j < KS; ++j)
                sQ[buf][tt][j] = softplus_f(acc[j]) + 1e-8f;
            float ag = bg2[0];
#pragma unroll 8
            for (int k = 0; k < 32; ++k) {
                float hk = bg1[k];
                hk = fmaf(pv.x, Wg1[k],      hk);
                hk = fmaf(pv.y, Wg1[32 + k], hk);
                hk = fmaf(pv.z, Wg1[64 + k], hk);
                hk = fmaf(pv.w, Wg1[96 + k], hk);
                hk = fmaxf(hk, 0.0f);
                ag = fmaf(hk, Wg2[k], ag);
            }
            sGf[buf][tt] = sigmoid_f(ag);
        } else {
            mlp16(pv, Wr1, br1, Wr2, br2, acc);
#pragma unroll
            for (int j = 0; j < KS; ++j)
                sR[buf][tt][j] = softplus_f(acc[j]) + 1e-8f;
        }
        const float4* __restrict__ zt =
            reinterpret_cast<const float4*>(zb + (size_t)tile * KTT * KS);
        float4* __restrict__ zd = reinterpret_cast<float4*>(&sZf[buf][0][0]);
        zd[tid] = zt[tid];
        zd[tid + 256] = zt[tid + 256];
    };

    float mu = 0.0f, Pv = 0.0f;
    if (!is_mlp) {
        const int lane = tid - 256;
        if (lane < KS) {
            mu = mu0[(size_t)b * KS + lane];
            Pv = P0[(size_t)b * KS + lane];
        }
    }

    if (is_mlp) do_mlp_tile(0, 0);
    __syncthreads();

    for (int k = 0; k < KNT; ++k) {
        const int cur = k & 1;
        if (is_mlp) {
            if (k + 1 < KNT) do_mlp_tile(k + 1, cur ^ 1);
        } else {
            const int lane = tid - 256;
            if (lane < KS) {
                const int s = lane;
                for (int tt = 0; tt < KTT; ++tt) {
                    const float Ppred = Pv + sQ[cur][tt][s];
                    float Kk = Ppred * __builtin_amdgcn_rcpf(Ppred + sR[cur][tt][s]);
                    Kk = __builtin_amdgcn_fmed3f(Kk, 1e-6f, 0.95f);
                    mu = fmaf(sGf[cur][tt] * Kk, sZf[cur][tt][s] - mu, mu);
                    Pv = fmaf(-Kk, Ppred, Ppred);
                    outb[(size_t)(k * KTT + tt) * KS + s] = mu;
                }
            }
        }
        __syncthreads();
    }
}

// ---------------- launcher ----------------
extern "C" void kernel_launch(void* const* d_in, const int* in_sizes, int n_in,
                              void* d_out, int out_size, void* d_ws, size_t ws_size,
                              hipStream_t stream) {
    const float* z   = (const float*)d_in[0];
    const float* p   = (const float*)d_in[1];
    const float* mu0 = (const float*)d_in[2];
    const float* P0  = (const float*)d_in[3];
    const float* Wq1 = (const float*)d_in[4];
    const float* bq1 = (const float*)d_in[5];
    const float* Wq2 = (const float*)d_in[6];
    const float* bq2 = (const float*)d_in[7];
    const float* Wr1 = (const float*)d_in[8];
    const float* br1 = (const float*)d_in[9];
    const float* Wr2 = (const float*)d_in[10];
    const float* br2 = (const float*)d_in[11];
    const float* Wg1 = (const float*)d_in[12];
    const float* bg1 = (const float*)d_in[13];
    const float* Wg2 = (const float*)d_in[14];
    const float* bg2 = (const float*)d_in[15];
    float* out = (float*)d_out;

    const size_t QR_BYTES = (size_t)KB * KS * KT * 4;   // 67,108,864
    const size_t G_BYTES  = (size_t)KB * KT * 4;        //  4,194,304

    if (ws_size >= QR_BYTES + G_BYTES) {
        uint32_t* qr_ws = (uint32_t*)d_ws;
        float* g_ws = (float*)((char*)d_ws + QR_BYTES);
        hipLaunchKernelGGL(mlp_kernel, dim3((KB * KT) / 256), dim3(256), 0, stream,
                           p, Wq1, bq1, Wq2, bq2, Wr1, br1, Wr2, br2,
                           Wg1, bg1, Wg2, bg2, qr_ws, g_ws);
        hipLaunchKernelGGL(scan_kernel, dim3(KB), dim3(64), 0, stream,
                           qr_ws, g_ws, z, mu0, P0, out);
    } else {
        hipLaunchKernelGGL(kalman_fused, dim3(KB), dim3(320), 0, stream,
                           z, p, mu0, P0, Wq1, bq1, Wq2, bq2,
                           Wr1, br1, Wr2, br2, Wg1, bg1, Wg2, bg2, out);
    }
}